// Round 9
// baseline (185.176 us; speedup 1.0000x reference)
//
#include <hip/hip_runtime.h>

typedef unsigned short u16;
typedef __attribute__((ext_vector_type(8))) _Float16 f16x8;
typedef __attribute__((ext_vector_type(4))) float f32x4;

#define MFMA_F16 __builtin_amdgcn_mfma_f32_16x16x32_f16

static __device__ __forceinline__ u16 f2h(float f) {
    return __builtin_bit_cast(u16, (_Float16)f);
}
static __device__ __forceinline__ ushort4 f4_to_h4(const float4 v) {
    ushort4 r;
    r.x = f2h(v.x); r.y = f2h(v.y); r.z = f2h(v.z); r.w = f2h(v.w);
    return r;
}
// async global->LDS, 16B per lane, dest = wave-uniform base + lane*16
static __device__ __forceinline__ void gl16(const u16* g, u16* l) {
    __builtin_amdgcn_global_load_lds(
        (__attribute__((address_space(1))) void*)(g),
        (__attribute__((address_space(3))) void*)(l),
        16, 0, 0);
}

// ---------------------------------------------------------------------------
// Kernel 0: prep_w — W fp32->fp16 and X fp32->fp16 (Xh in d_out scratch).
// (R20, measured good — unchanged.)
// ---------------------------------------------------------------------------
__global__ __launch_bounds__(256) void prep_w(
    const float* __restrict__ wq, const float* __restrict__ wk,
    const float* __restrict__ wv, const float* __restrict__ wo,
    const float* __restrict__ x,
    u16* __restrict__ w4, u16* __restrict__ xh)
{
    const int tid = blockIdx.x * 256 + threadIdx.x;   // 65536 threads
    {
        const float* src = (tid < 16384) ? wq : (tid < 32768) ? wk
                         : (tid < 49152) ? wv : wo;
        ((ushort4*)w4)[tid] = f4_to_h4(((const float4*)src)[tid & 16383]);
    }
#pragma unroll
    for (int i = 0; i < 16; ++i) {
        const int j = i * 65536 + tid;                // 1048576 float4 of X
        ((ushort4*)xh)[j] = f4_to_h4(((const float4*)x)[j]);
    }
}

// ---------------------------------------------------------------------------
// Kernel 1: Q/K/V projection (R20 pipelined version, measured good —
// unchanged): gload_lds dbuf, raw s_barrier + vmcnt(0), XOR swizzle.
// ---------------------------------------------------------------------------
__global__ __launch_bounds__(256, 3) void proj_qkv(
    const u16* __restrict__ Xh, const u16* __restrict__ w4,
    const float* __restrict__ bq, const float* __restrict__ bk,
    const float* __restrict__ bv,
    u16* __restrict__ Qh, u16* __restrict__ Kh, u16* __restrict__ Vt)
{
    const int z = blockIdx.y;
    const u16* __restrict__ W     = w4 + z * 65536;
    const float* __restrict__ bias = (z == 0) ? bq : (z == 1) ? bk : bv;

    const int m0   = blockIdx.x * 64;          // global row (b*2048 + n0)
    const int t    = threadIdx.x;
    const int w    = t >> 6;
    const int lane = t & 63;
    const int quad = lane >> 4;
    const int l16  = lane & 15;

    // [X 2048 u16][W 8192 u16] per buffer x 2 = 20480 u16 (40960 B)
    __shared__ __align__(16) u16 smem[20480];

    const int xrow = t >> 2, xpp = t & 3;
    const unsigned xsrc = (unsigned)((m0 + xrow) * 256
                        + ((xpp ^ ((xrow >> 1) & 3)) * 8));
    unsigned wsrc[4];
#pragma unroll
    for (int i = 0; i < 4; ++i) {
        const int j = i * 256 + t;
        const int row = j >> 2, p = j & 3;
        wsrc[i] = (unsigned)(row * 256 + ((p ^ ((row >> 1) & 3)) * 8));
    }

#define PSTAGE(bufsel, kc_) do {                                             \
        u16* B_ = smem + (bufsel) * 10240;                                   \
        gl16(Xh + xsrc + (unsigned)(kc_) * 32, B_ + w * 512);                \
        _Pragma("unroll")                                                    \
        for (int i_ = 0; i_ < 4; ++i_)                                       \
            gl16(W + wsrc[i_] + (unsigned)(kc_) * 32,                        \
                 B_ + 2048 + i_ * 2048 + w * 512);                           \
    } while (0)

    f32x4 acc[16];
#pragma unroll
    for (int i = 0; i < 16; ++i) acc[i] = f32x4{0.f, 0.f, 0.f, 0.f};

    const int rp = (quad ^ ((l16 >> 1) & 3)) * 8;   // swizzled read offset

    PSTAGE(0, 0);

    for (int kc = 0; kc < 8; ++kc) {
        asm volatile("s_waitcnt vmcnt(0)" ::: "memory");
        __builtin_amdgcn_s_barrier();
        __builtin_amdgcn_sched_barrier(0);
        if (kc + 1 < 8) PSTAGE((kc + 1) & 1, kc + 1);
        __builtin_amdgcn_sched_barrier(0);

        const u16* Xb = smem + (kc & 1) * 10240;
        const u16* Wb = Xb + 2048;

        const f16x8 af = *(const f16x8*)&Xb[(w * 16 + l16) * 32 + rp];
        __builtin_amdgcn_s_setprio(1);
#pragma unroll
        for (int nt = 0; nt < 16; ++nt) {
            const f16x8 bf = *(const f16x8*)&Wb[(nt * 16 + l16) * 32 + rp];
            acc[nt] = MFMA_F16(af, bf, acc[nt], 0, 0, 0);
        }
        __builtin_amdgcn_s_setprio(0);
    }
#undef PSTAGE

    __syncthreads();   // all waves done with LDS before epilogue reuse

    if (z < 2) {
        u16* __restrict__ Y = (z == 0) ? Qh : Kh;
#pragma unroll
        for (int nt = 0; nt < 16; ++nt) {
            const int col = nt * 16 + l16;
            const float bb = bias[col];
#pragma unroll
            for (int r = 0; r < 4; ++r)
                smem[(w * 16 + quad * 4 + r) * 264 + col] = f2h(acc[nt][r] + bb);
        }
        __syncthreads();
#pragma unroll
        for (int i = 0; i < 8; ++i) {
            const int ch = i * 256 + t;
            const int row = ch >> 5, cg = ch & 31;
            *(int4*)&Y[(size_t)(m0 + row) * 256 + cg * 8] =
                *(const int4*)&smem[row * 264 + cg * 8];
        }
    } else {
        const int b  = m0 >> 11;
        const int n0 = m0 & 2047;
#pragma unroll
        for (int nt = 0; nt < 16; ++nt) {
            const int col = nt * 16 + l16;
            const float bb = bias[col];
            ushort4 h4;
            h4.x = f2h(acc[nt][0] + bb);
            h4.y = f2h(acc[nt][1] + bb);
            h4.z = f2h(acc[nt][2] + bb);
            h4.w = f2h(acc[nt][3] + bb);
            *(ushort4*)&smem[col * 72 + w * 16 + quad * 4] = h4;
        }
        __syncthreads();
#pragma unroll
        for (int i = 0; i < 8; ++i) {
            const int ch = i * 256 + t;
            const int row = ch >> 3, cg = ch & 7;
            *(int4*)&Vt[(size_t)b * 524288 + (size_t)row * 2048 + n0 + cg * 8] =
                *(const int4*)&smem[row * 72 + cg * 8];
        }
    }
}

// ---------------------------------------------------------------------------
// Kernel 2: flash attention. R21: LDS-bandwidth attack.
// R19's pipeline left all pipes <26%; arithmetic shows LDS traffic
// (1KB A-frag per MFMA x 32/wave/tile) = 2.1GB = 32 TB/s at 65.7µs = 46%
// of the 69TB/s LDS ceiling with only 8 waves/CU. Per-wave code is already
// minimal (B-operands Q,P in regs). Fix: QBLK 64->128, 512-thread blocks
// (8 waves), per-wave work byte-identical -> 16 waves/CU (2 blocks x 8,
// LDS 69.6KB/block incl. epilogue, 139KB/CU) to saturate the LDS pipe.
// nz=4 -> grid 16x8x4 = 512 = exactly 2/CU. Partials z=2,3 packed in d_out
// (Xh dead by now; R13/R14-proven layout), l[4]/m[4] in dead-W/old-lmp slots.
// ---------------------------------------------------------------------------
__global__ __launch_bounds__(512, 4) void attn(
    const u16* __restrict__ Qh, const u16* __restrict__ Kg,
    const u16* __restrict__ Vt, u16* __restrict__ Op,
    u16* __restrict__ OutS, float* __restrict__ lmpL, float* __restrict__ lmpM)
{
    const int nz = gridDim.z;          // 4
    const int z  = blockIdx.z;
    const int ntiles = 64 / nz;        // 16 tiles of 32 keys
    const int tile0  = ntiles * z;

    const int b  = blockIdx.y;
    const int q0 = blockIdx.x * 128;
    const int t    = threadIdx.x;
    const int w    = t >> 6;           // 0..7
    const int lane = t & 63;
    const int quad = lane >> 4;
    const int l16  = lane & 15;

    // [K0 8192][V0 8192][K1 8192][V1 8192] u16 = 64KB; epilogue Os needs
    // 128 x 264 u16 = 33792 -> allocate 34816 u16 (69632 B).
    __shared__ __align__(16) u16 smem[34816];
    u16* Os = smem;

    f16x8 qf[8];
    {
        const size_t qrow = (size_t)(b * 2048 + q0 + w * 16 + l16) * 256;
#pragma unroll
        for (int kc = 0; kc < 8; ++kc)
            qf[kc] = *(const f16x8*)&Qh[qrow + kc * 32 + quad * 8];
    }

    // per-thread staging source bases (tile-invariant, u16 indices)
    unsigned kgb[2], vgb[2];
#pragma unroll
    for (int i = 0; i < 2; ++i) {
        const int j  = w * 2 + i;                           // 0..15
        const int r  = 2 * j + (lane >> 5);                 // K LDS row 0..31
        const int pr = ((r >> 2) & 3) * 8 + (r >> 4) * 4 + (r & 3);
        const int c  = lane & 31;                           // 16B chunk in row
        kgb[i] = (unsigned)((b * 2048 + pr) * 256 + ((c ^ (r & 7)) * 8));
        const int rp2 = 8 * j + (lane >> 3);                // V LDS row 0..127
        const int c8 = lane & 7;                            // 16B chunk in row
        const int d  = 2 * rp2 + (c8 >> 2);                 // d-row 0..255
        const int a  = (c8 & 3) ^ (rp2 & 3);                // actual key-chunk
        vgb[i] = (unsigned)(b * 524288 + d * 2048 + a * 8);
    }

#define STAGE(bufsel, kt_) do {                                              \
        u16* Kb_ = smem + (bufsel) * 16384;                                  \
        u16* Vb_ = Kb_ + 8192;                                               \
        _Pragma("unroll")                                                    \
        for (int i_ = 0; i_ < 2; ++i_) {                                     \
            gl16(Kg + kgb[i_] + (unsigned)(kt_) * 256,                       \
                 Kb_ + (w * 2 + i_) * 512);                                  \
            gl16(Vt + vgb[i_] + (unsigned)(kt_),                             \
                 Vb_ + (w * 2 + i_) * 512);                                  \
        }                                                                    \
    } while (0)

    f32x4 O[16];
#pragma unroll
    for (int i = 0; i < 16; ++i) O[i] = f32x4{0.f, 0.f, 0.f, 0.f};
    float mrow = -1e30f, lrow = 0.f;

    const int vbase = (l16 >> 1) * 64 + (l16 & 1) * 32
                    + ((quad ^ ((l16 >> 1) & 3)) * 8);

    STAGE(0, tile0 * 32);

    for (int it = 0; it < ntiles; ++it) {
        asm volatile("s_waitcnt vmcnt(0)" ::: "memory");
        __builtin_amdgcn_s_barrier();
        __builtin_amdgcn_sched_barrier(0);
        if (it + 1 < ntiles) STAGE((it + 1) & 1, (tile0 + it + 1) * 32);
        __builtin_amdgcn_sched_barrier(0);

        const u16* Kc = smem + (it & 1) * 16384;
        const u16* Vc = Kc + 8192;

        f32x4 S[2];
        S[0] = f32x4{0.f, 0.f, 0.f, 0.f};
        S[1] = f32x4{0.f, 0.f, 0.f, 0.f};
        __builtin_amdgcn_s_setprio(1);
#pragma unroll
        for (int kc = 0; kc < 8; ++kc) {
#pragma unroll
            for (int kn = 0; kn < 2; ++kn) {
                const int r2 = kn * 16 + l16;
                const f16x8 kf = *(const f16x8*)
                    &Kc[r2 * 256 + (((kc * 4 + quad) ^ (l16 & 7)) * 8)];
                S[kn] = MFMA_F16(kf, qf[kc], S[kn], 0, 0, 0);
            }
        }
        __builtin_amdgcn_s_setprio(0);

        float mt = fmaxf(fmaxf(fmaxf(S[0][0], S[0][1]), fmaxf(S[0][2], S[0][3])),
                         fmaxf(fmaxf(S[1][0], S[1][1]), fmaxf(S[1][2], S[1][3])));
        mt = fmaxf(mt, __shfl_xor(mt, 16));
        mt = fmaxf(mt, __shfl_xor(mt, 32));
        // T13 defer-max: rescale only when tile max grows past mrow+8.
        if (__any(mt - mrow > 8.f)) {
            const float mnew = fmaxf(mrow, mt);
            const float a = __expf(mrow - mnew);
            lrow *= a;
#pragma unroll
            for (int dv = 0; dv < 16; ++dv)
#pragma unroll
                for (int r = 0; r < 4; ++r) O[dv][r] *= a;
            mrow = mnew;
        }
        f16x8 pfv;
        float s = 0.f;
#pragma unroll
        for (int kn = 0; kn < 2; ++kn)
#pragma unroll
            for (int r = 0; r < 4; ++r) {
                const float e = __expf(S[kn][r] - mrow);
                s += e;
                pfv[kn * 4 + r] = (_Float16)e;
            }
        s += __shfl_xor(s, 16);
        s += __shfl_xor(s, 32);
        lrow += s;

        __builtin_amdgcn_s_setprio(1);
#pragma unroll
        for (int dvt = 0; dvt < 16; ++dvt) {
            const f16x8 vf = *(const f16x8*)&Vc[dvt * 512 + vbase];
            O[dvt] = MFMA_F16(vf, pfv, O[dvt], 0, 0, 0);
        }
        __builtin_amdgcn_s_setprio(0);
    }
#undef STAGE

    __syncthreads();   // all waves done with last tile before smem reuse
    {
        const float rl = 1.0f / lrow;
#pragma unroll
        for (int dvt = 0; dvt < 16; ++dvt) {
            ushort4 h4;
            h4.x = f2h(O[dvt][0] * rl);
            h4.y = f2h(O[dvt][1] * rl);
            h4.z = f2h(O[dvt][2] * rl);
            h4.w = f2h(O[dvt][3] * rl);
            *(ushort4*)&Os[(w * 16 + l16) * 264 + dvt * 16 + quad * 4] = h4;
        }
        if (quad == 0) {
            const int grow = b * 2048 + q0 + w * 16 + l16;
            lmpL[z * 16384 + grow] = lrow;
            lmpM[z * 16384 + grow] = mrow;
        }
    }
    __syncthreads();

    {
        const int row = t >> 2;            // 0..127
        if (z < 2) {
            u16* __restrict__ Oz = Op + (size_t)z * 4194304;
#pragma unroll
            for (int i = 0; i < 8; ++i) {
                const int chunk = (t & 3) * 8 + i;
                *(int4*)&Oz[(size_t)(b * 2048 + q0 + row) * 256 + chunk * 8] =
                    *(const int4*)&Os[row * 264 + chunk * 8];
            }
        } else {
            // packed into d_out scratch: row m -> u16[m*512 + (z-2)*256 ...]
            u16* __restrict__ Oz = OutS + (size_t)(z - 2) * 256;
#pragma unroll
            for (int i = 0; i < 8; ++i) {
                const int chunk = (t & 3) * 8 + i;
                *(int4*)&Oz[(size_t)(b * 2048 + q0 + row) * 512 + chunk * 8] =
                    *(const int4*)&Os[row * 264 + chunk * 8];
            }
        }
    }
}

// ---------------------------------------------------------------------------
// Kernel 3: combine 4 partials + out projection + LayerNorm + LeakyReLU.
// R18 32-row structure + R14-proven 4-partial combine (z=2,3 from d_out
// scratch, read fully for rows m0..m0+31 before the epilogue overwrites
// exactly those rows -> no hazard).
// ---------------------------------------------------------------------------
__global__ __launch_bounds__(256, 2) void outproj_ln(
    const u16* __restrict__ Op, const u16* __restrict__ OutS,
    const float* __restrict__ lmpL, const float* __restrict__ lmpM,
    const u16* __restrict__ Woh, const float* __restrict__ bo,
    const float* __restrict__ gamma, const float* __restrict__ beta,
    float* __restrict__ out)
{
    const int m0   = blockIdx.x * 32;
    const int t    = threadIdx.x;
    const int w    = t >> 6;
    const int rw   = w & 1;        // row-group (16 rows)
    const int cw   = w >> 1;       // col-half (128 cols)
    const int lane = t & 63;
    const int quad = lane >> 4;
    const int l16  = lane & 15;

    __shared__ __align__(16) u16 Ls[32 * 40];
    __shared__ __align__(16) u16 Ws[256 * 40];
    __shared__ _Float16 wls[4][32];
    __shared__ float part[2][16][2][2];   // [rw][row16][cw][{sh,sh2}]

    if (t < 32) {
        const float l0 = lmpL[m0 + t];
        const float l1 = lmpL[16384 + m0 + t];
        const float l2 = lmpL[32768 + m0 + t];
        const float l3 = lmpL[49152 + m0 + t];
        const float m0v = lmpM[m0 + t];
        const float m1v = lmpM[16384 + m0 + t];
        const float m2v = lmpM[32768 + m0 + t];
        const float m3v = lmpM[49152 + m0 + t];
        const float mm = fmaxf(fmaxf(m0v, m1v), fmaxf(m2v, m3v));
        const float u0 = l0 * __expf(m0v - mm);
        const float u1 = l1 * __expf(m1v - mm);
        const float u2 = l2 * __expf(m2v - mm);
        const float u3 = l3 * __expf(m3v - mm);
        const float inv = 1.0f / (u0 + u1 + u2 + u3);
        wls[0][t] = (_Float16)(u0 * inv);
        wls[1][t] = (_Float16)(u1 * inv);
        wls[2][t] = (_Float16)(u2 * inv);
        wls[3][t] = (_Float16)(u3 * inv);
    }
    __syncthreads();

    f32x4 acc[8];
#pragma unroll
    for (int i = 0; i < 8; ++i) acc[i] = f32x4{0.f, 0.f, 0.f, 0.f};

    for (int kc = 0; kc < 8; ++kc) {
        if (t < 128) {
            const int row = t >> 2, cg = t & 3;
            const size_t off  = (size_t)(m0 + row) * 256 + kc * 32 + cg * 8;
            const size_t offS = (size_t)(m0 + row) * 512 + kc * 32 + cg * 8;
            const f16x8 o0 = __builtin_bit_cast(f16x8, *(const int4*)&Op[off]);
            const f16x8 o1 = __builtin_bit_cast(f16x8, *(const int4*)&Op[4194304 + off]);
            const f16x8 o2 = __builtin_bit_cast(f16x8, *(const int4*)&OutS[offS]);
            const f16x8 o3 = __builtin_bit_cast(f16x8, *(const int4*)&OutS[offS + 256]);
            const _Float16 w0 = wls[0][row], w1 = wls[1][row];
            const _Float16 w2 = wls[2][row], w3 = wls[3][row];
            f16x8 lw;
#pragma unroll
            for (int j = 0; j < 8; ++j)
                lw[j] = o0[j] * w0 + o1[j] * w1 + o2[j] * w2 + o3[j] * w3;
            *(int4*)&Ls[row * 40 + cg * 8] = __builtin_bit_cast(int4, lw);
        }
#pragma unroll
        for (int i = 0; i < 4; ++i) {
            const int ch = i * 256 + t;
            const int row = ch >> 2, cg = ch & 3;
            *(int4*)&Ws[row * 40 + cg * 8] =
                *(const int4*)&Woh[(size_t)row * 256 + kc * 32 + cg * 8];
        }
        __syncthreads();

        const f16x8 af = *(const f16x8*)&Ls[(rw * 16 + l16) * 40 + quad * 8];
#pragma unroll
        for (int nt = 0; nt < 8; ++nt) {
            const f16x8 bf = *(const f16x8*)&Ws[((cw * 8 + nt) * 16 + l16) * 40 + quad * 8];
            acc[nt] = MFMA_F16(af, bf, acc[nt], 0, 0, 0);
        }
        __syncthreads();
    }

    float g[8], bt[8], bb[8];
#pragma unroll
    for (int nt = 0; nt < 8; ++nt) {
        const int col = cw * 128 + nt * 16 + l16;
        bb[nt] = bo[col]; g[nt] = gamma[col]; bt[nt] = beta[col];
    }

    float shv[4], sh2v[4];
#pragma unroll
    for (int r = 0; r < 4; ++r) {
        float sh = 0.f, sh2 = 0.f;
#pragma unroll
        for (int nt = 0; nt < 8; ++nt) {
            const float h = acc[nt][r] + bb[nt];
            sh  += h;
            sh2 += h * h;
        }
        sh  += __shfl_xor(sh, 1);  sh  += __shfl_xor(sh, 2);
        sh  += __shfl_xor(sh, 4);  sh  += __shfl_xor(sh, 8);
        sh2 += __shfl_xor(sh2, 1); sh2 += __shfl_xor(sh2, 2);
        sh2 += __shfl_xor(sh2, 4); sh2 += __shfl_xor(sh2, 8);
        shv[r] = sh; sh2v[r] = sh2;
    }
    if (l16 == 0) {
#pragma unroll
        for (int r = 0; r < 4; ++r) {
            part[rw][quad * 4 + r][cw][0] = shv[r];
            part[rw][quad * 4 + r][cw][1] = sh2v[r];
        }
    }
    __syncthreads();

#pragma unroll
    for (int r = 0; r < 4; ++r) {
        const float sh  = shv[r]  + part[rw][quad * 4 + r][cw ^ 1][0];
        const float sh2 = sh2v[r] + part[rw][quad * 4 + r][cw ^ 1][1];
        const float mu  = sh * (1.f / 256.f);
        const float var = fmaxf(sh2 * (1.f / 256.f) - mu * mu, 0.f);
        const float rs  = rsqrtf(var + 1e-5f);
        const size_t row = (size_t)(m0 + rw * 16 + quad * 4 + r) * 256;
#pragma unroll
        for (int nt = 0; nt < 8; ++nt) {
            const float hn = (acc[nt][r] + bb[nt] - mu) * rs * g[nt] + bt[nt];
            out[row + cw * 128 + nt * 16 + l16] = (hn >= 0.f) ? hn : 0.01f * hn;
        }
    }
}

// ---------------------------------------------------------------------------
extern "C" void kernel_launch(void* const* d_in, const int* in_sizes, int n_in,
                              void* d_out, int out_size, void* d_ws, size_t ws_size,
                              hipStream_t stream)
{
    const float* x  = (const float*)d_in[0];
    const float* Wq = (const float*)d_in[1];
    const float* bq = (const float*)d_in[2];
    const float* Wk = (const float*)d_in[3];
    const float* bk = (const float*)d_in[4];
    const float* Wv = (const float*)d_in[5];
    const float* bv = (const float*)d_in[6];
    const float* Wo = (const float*)d_in[7];
    const float* bo = (const float*)d_in[8];
    const float* gm = (const float*)d_in[9];
    const float* bt = (const float*)d_in[10];
    float* out = (float*)d_out;

    // ws layout (u16): [W4 262144][Qh 4.19M][Kh 4.19M][Vt 4.19M][Op 2x4.19M][lmpM]
    // -> identical total d_ws footprint to the baseline.
    // d_out scratch lifecycle: prep_w writes Xh -> proj_qkv reads Xh ->
    // attn overwrites d_out with partials z=2,3 -> outproj reads them and
    // writes the final f32 output.
    // l[4] stats in dead Wq/Wk/Wv half of W4 (384KB, dead after proj);
    // m[4] stats in the old lmp slot.
    u16* W4 = (u16*)d_ws;
    u16* Qh = W4 + 262144;
    u16* Kh = Qh + 4194304;
    u16* Vt = Kh + 4194304;
    u16* Op = Vt + 4194304;
    float* lmpM = (float*)(Op + 2 * 4194304);  // m[4][16384]
    float* lmpL = (float*)W4;                  // l[4][16384] (dead W region)
    u16* Woh = W4 + 196608;
    u16* Xh  = (u16*)d_out;
    u16* OutS = (u16*)d_out;

    prep_w     <<<256,            256, 0, stream>>>(Wq, Wk, Wv, Wo, x, W4, Xh);
    proj_qkv   <<<dim3(256, 3),   256, 0, stream>>>(Xh, W4, bq, bk, bv, Qh, Kh, Vt);
    attn       <<<dim3(16, 8, 4), 512, 0, stream>>>(Qh, Kh, Vt, Op, OutS, lmpL, lmpM);
    outproj_ln <<<512,            256, 0, stream>>>(Op, OutS, lmpL, lmpM, Woh, bo, gm, bt, out);
}

// Round 10
// 168.247 us; speedup vs baseline: 1.1006x; 1.1006x over previous
//
#include <hip/hip_runtime.h>

typedef unsigned short u16;
typedef __attribute__((ext_vector_type(8))) _Float16 f16x8;
typedef __attribute__((ext_vector_type(4))) float f32x4;

#define MFMA_F16 __builtin_amdgcn_mfma_f32_16x16x32_f16

static __device__ __forceinline__ u16 f2h(float f) {
    return __builtin_bit_cast(u16, (_Float16)f);
}
static __device__ __forceinline__ ushort4 f4_to_h4(const float4 v) {
    ushort4 r;
    r.x = f2h(v.x); r.y = f2h(v.y); r.z = f2h(v.z); r.w = f2h(v.w);
    return r;
}
// async global->LDS, 16B per lane, dest = wave-uniform base + lane*16
static __device__ __forceinline__ void gl16(const u16* g, u16* l) {
    __builtin_amdgcn_global_load_lds(
        (__attribute__((address_space(1))) void*)(g),
        (__attribute__((address_space(3))) void*)(l),
        16, 0, 0);
}

// ---------------------------------------------------------------------------
// Kernel 0: prep_w — W fp32->fp16 and X fp32->fp16 (Xh in d_out scratch).
// (R20, measured good — unchanged.)
// ---------------------------------------------------------------------------
__global__ __launch_bounds__(256) void prep_w(
    const float* __restrict__ wq, const float* __restrict__ wk,
    const float* __restrict__ wv, const float* __restrict__ wo,
    const float* __restrict__ x,
    u16* __restrict__ w4, u16* __restrict__ xh)
{
    const int tid = blockIdx.x * 256 + threadIdx.x;   // 65536 threads
    {
        const float* src = (tid < 16384) ? wq : (tid < 32768) ? wk
                         : (tid < 49152) ? wv : wo;
        ((ushort4*)w4)[tid] = f4_to_h4(((const float4*)src)[tid & 16383]);
    }
#pragma unroll
    for (int i = 0; i < 16; ++i) {
        const int j = i * 65536 + tid;                // 1048576 float4 of X
        ((ushort4*)xh)[j] = f4_to_h4(((const float4*)x)[j]);
    }
}

// ---------------------------------------------------------------------------
// Kernel 1: Q/K/V projection (R20 pipelined version, measured good —
// unchanged): gload_lds dbuf, raw s_barrier + vmcnt(0), XOR swizzle.
// ---------------------------------------------------------------------------
__global__ __launch_bounds__(256, 3) void proj_qkv(
    const u16* __restrict__ Xh, const u16* __restrict__ w4,
    const float* __restrict__ bq, const float* __restrict__ bk,
    const float* __restrict__ bv,
    u16* __restrict__ Qh, u16* __restrict__ Kh, u16* __restrict__ Vt)
{
    const int z = blockIdx.y;
    const u16* __restrict__ W     = w4 + z * 65536;
    const float* __restrict__ bias = (z == 0) ? bq : (z == 1) ? bk : bv;

    const int m0   = blockIdx.x * 64;          // global row (b*2048 + n0)
    const int t    = threadIdx.x;
    const int w    = t >> 6;
    const int lane = t & 63;
    const int quad = lane >> 4;
    const int l16  = lane & 15;

    // [X 2048 u16][W 8192 u16] per buffer x 2 = 20480 u16 (40960 B)
    __shared__ __align__(16) u16 smem[20480];

    const int xrow = t >> 2, xpp = t & 3;
    const unsigned xsrc = (unsigned)((m0 + xrow) * 256
                        + ((xpp ^ ((xrow >> 1) & 3)) * 8));
    unsigned wsrc[4];
#pragma unroll
    for (int i = 0; i < 4; ++i) {
        const int j = i * 256 + t;
        const int row = j >> 2, p = j & 3;
        wsrc[i] = (unsigned)(row * 256 + ((p ^ ((row >> 1) & 3)) * 8));
    }

#define PSTAGE(bufsel, kc_) do {                                             \
        u16* B_ = smem + (bufsel) * 10240;                                   \
        gl16(Xh + xsrc + (unsigned)(kc_) * 32, B_ + w * 512);                \
        _Pragma("unroll")                                                    \
        for (int i_ = 0; i_ < 4; ++i_)                                       \
            gl16(W + wsrc[i_] + (unsigned)(kc_) * 32,                        \
                 B_ + 2048 + i_ * 2048 + w * 512);                           \
    } while (0)

    f32x4 acc[16];
#pragma unroll
    for (int i = 0; i < 16; ++i) acc[i] = f32x4{0.f, 0.f, 0.f, 0.f};

    const int rp = (quad ^ ((l16 >> 1) & 3)) * 8;   // swizzled read offset

    PSTAGE(0, 0);

    for (int kc = 0; kc < 8; ++kc) {
        asm volatile("s_waitcnt vmcnt(0)" ::: "memory");
        __builtin_amdgcn_s_barrier();
        __builtin_amdgcn_sched_barrier(0);
        if (kc + 1 < 8) PSTAGE((kc + 1) & 1, kc + 1);
        __builtin_amdgcn_sched_barrier(0);

        const u16* Xb = smem + (kc & 1) * 10240;
        const u16* Wb = Xb + 2048;

        const f16x8 af = *(const f16x8*)&Xb[(w * 16 + l16) * 32 + rp];
        __builtin_amdgcn_s_setprio(1);
#pragma unroll
        for (int nt = 0; nt < 16; ++nt) {
            const f16x8 bf = *(const f16x8*)&Wb[(nt * 16 + l16) * 32 + rp];
            acc[nt] = MFMA_F16(af, bf, acc[nt], 0, 0, 0);
        }
        __builtin_amdgcn_s_setprio(0);
    }
#undef PSTAGE

    __syncthreads();   // all waves done with LDS before epilogue reuse

    if (z < 2) {
        u16* __restrict__ Y = (z == 0) ? Qh : Kh;
#pragma unroll
        for (int nt = 0; nt < 16; ++nt) {
            const int col = nt * 16 + l16;
            const float bb = bias[col];
#pragma unroll
            for (int r = 0; r < 4; ++r)
                smem[(w * 16 + quad * 4 + r) * 264 + col] = f2h(acc[nt][r] + bb);
        }
        __syncthreads();
#pragma unroll
        for (int i = 0; i < 8; ++i) {
            const int ch = i * 256 + t;
            const int row = ch >> 5, cg = ch & 31;
            *(int4*)&Y[(size_t)(m0 + row) * 256 + cg * 8] =
                *(const int4*)&smem[row * 264 + cg * 8];
        }
    } else {
        const int b  = m0 >> 11;
        const int n0 = m0 & 2047;
#pragma unroll
        for (int nt = 0; nt < 16; ++nt) {
            const int col = nt * 16 + l16;
            const float bb = bias[col];
            ushort4 h4;
            h4.x = f2h(acc[nt][0] + bb);
            h4.y = f2h(acc[nt][1] + bb);
            h4.z = f2h(acc[nt][2] + bb);
            h4.w = f2h(acc[nt][3] + bb);
            *(ushort4*)&smem[col * 72 + w * 16 + quad * 4] = h4;
        }
        __syncthreads();
#pragma unroll
        for (int i = 0; i < 8; ++i) {
            const int ch = i * 256 + t;
            const int row = ch >> 3, cg = ch & 7;
            *(int4*)&Vt[(size_t)b * 524288 + (size_t)row * 2048 + n0 + cg * 8] =
                *(const int4*)&smem[row * 72 + cg * 8];
        }
    }
}

// ---------------------------------------------------------------------------
// Kernel 2: flash attention. R22 = R19 (measured 63.3µs) + XCD-chunked
// block swizzle (T1).
// R21 post-mortem: 512-thread/16-wave config forces a 128-reg cap -> spill
// (VGPR 64, WRITE_SIZE 76MB); per-thread state ~150-170 regs is irreducible,
// so 8 waves/CU at 2 blocks is the feasible region. Reverted.
// T1 rationale: FETCH 70MB vs ~28MB ideal -> K/V re-reads miss L2. Default
// round-robin gives each XCD all 8 batches (16MB KV >> 4MB L2). Chunked
// remap swz=(lin&7)*64+(lin>>3) (bijective, 512%8==0) gives each XCD 64
// contiguous logical blocks = 2 (b,z) groups = 2MB KV -> L2-resident ->
// HBM-miss latency (~900cy) off the vmcnt(0) critical path.
// ---------------------------------------------------------------------------
__global__ __launch_bounds__(256, 2) void attn(
    const u16* __restrict__ Qh, const u16* __restrict__ Kg,
    const u16* __restrict__ Vt, u16* __restrict__ Op, float* __restrict__ lmp)
{
    const int nz = gridDim.z;          // 2
    // XCD-chunked swizzle: original linear id -> logical (q0, b, z)
    int lin = blockIdx.x + 32 * (blockIdx.y + 8 * blockIdx.z);
    lin = (lin & 7) * 64 + (lin >> 3);
    const int q0 = (lin & 31) * 64;
    const int b  = (lin >> 5) & 7;
    const int z  = lin >> 8;

    const int ntiles = 32;             // 64 tiles / nz
    const int tile0  = ntiles * z;

    const int t    = threadIdx.x;
    const int w    = t >> 6;
    const int lane = t & 63;
    const int quad = lane >> 4;
    const int l16  = lane & 15;

    // [K0 8192][V0 8192][K1 8192][V1 8192] u16 = 65536 B
    __shared__ __align__(16) u16 smem[32768];
    u16* Os = smem;                // epilogue reuse: 64 x 264 (16896 u16)

    f16x8 qf[8];
    {
        const size_t qrow = (size_t)(b * 2048 + q0 + w * 16 + l16) * 256;
#pragma unroll
        for (int kc = 0; kc < 8; ++kc)
            qf[kc] = *(const f16x8*)&Qh[qrow + kc * 32 + quad * 8];
    }

    // per-thread staging source bases (tile-invariant, u16 indices)
    unsigned kgb[4], vgb[4];
#pragma unroll
    for (int i = 0; i < 4; ++i) {
        const int j  = w * 4 + i;
        const int r  = 2 * j + (lane >> 5);                 // K LDS row 0..31
        const int pr = ((r >> 2) & 3) * 8 + (r >> 4) * 4 + (r & 3);
        const int c  = lane & 31;                           // 16B chunk in row
        kgb[i] = (unsigned)((b * 2048 + pr) * 256 + ((c ^ (r & 7)) * 8));
        const int rp2 = 8 * j + (lane >> 3);                // V LDS row 0..127
        const int c8 = lane & 7;                            // 16B chunk in row
        const int d  = 2 * rp2 + (c8 >> 2);                 // d-row 0..255
        const int a  = (c8 & 3) ^ (rp2 & 3);                // actual key-chunk
        vgb[i] = (unsigned)(b * 524288 + d * 2048 + a * 8);
    }

#define STAGE(bufsel, kt_) do {                                              \
        u16* Kb_ = smem + (bufsel) * 16384;                                  \
        u16* Vb_ = Kb_ + 8192;                                               \
        _Pragma("unroll")                                                    \
        for (int i_ = 0; i_ < 4; ++i_) {                                     \
            gl16(Kg + kgb[i_] + (unsigned)(kt_) * 256,                       \
                 Kb_ + (w * 4 + i_) * 512);                                  \
            gl16(Vt + vgb[i_] + (unsigned)(kt_),                             \
                 Vb_ + (w * 4 + i_) * 512);                                  \
        }                                                                    \
    } while (0)

    f32x4 O[16];
#pragma unroll
    for (int i = 0; i < 16; ++i) O[i] = f32x4{0.f, 0.f, 0.f, 0.f};
    float mrow = -1e30f, lrow = 0.f;

    // V read base (thread-invariant part)
    const int vbase = (l16 >> 1) * 64 + (l16 & 1) * 32
                    + ((quad ^ ((l16 >> 1) & 3)) * 8);

    STAGE(0, tile0 * 32);

    for (int it = 0; it < ntiles; ++it) {
        asm volatile("s_waitcnt vmcnt(0)" ::: "memory");
        __builtin_amdgcn_s_barrier();
        __builtin_amdgcn_sched_barrier(0);
        if (it + 1 < ntiles) STAGE((it + 1) & 1, (tile0 + it + 1) * 32);
        __builtin_amdgcn_sched_barrier(0);

        const u16* Kc = smem + (it & 1) * 16384;
        const u16* Vc = Kc + 8192;

        f32x4 S[2];
        S[0] = f32x4{0.f, 0.f, 0.f, 0.f};
        S[1] = f32x4{0.f, 0.f, 0.f, 0.f};
        __builtin_amdgcn_s_setprio(1);
#pragma unroll
        for (int kc = 0; kc < 8; ++kc) {
#pragma unroll
            for (int kn = 0; kn < 2; ++kn) {
                const int r2 = kn * 16 + l16;
                const f16x8 kf = *(const f16x8*)
                    &Kc[r2 * 256 + (((kc * 4 + quad) ^ (l16 & 7)) * 8)];
                S[kn] = MFMA_F16(kf, qf[kc], S[kn], 0, 0, 0);
            }
        }
        __builtin_amdgcn_s_setprio(0);

        float mt = fmaxf(fmaxf(fmaxf(S[0][0], S[0][1]), fmaxf(S[0][2], S[0][3])),
                         fmaxf(fmaxf(S[1][0], S[1][1]), fmaxf(S[1][2], S[1][3])));
        mt = fmaxf(mt, __shfl_xor(mt, 16));
        mt = fmaxf(mt, __shfl_xor(mt, 32));
        // T13 defer-max: rescale only when tile max grows past mrow+8.
        if (__any(mt - mrow > 8.f)) {
            const float mnew = fmaxf(mrow, mt);
            const float a = __expf(mrow - mnew);
            lrow *= a;
#pragma unroll
            for (int dv = 0; dv < 16; ++dv)
#pragma unroll
                for (int r = 0; r < 4; ++r) O[dv][r] *= a;
            mrow = mnew;
        }
        f16x8 pfv;
        float s = 0.f;
#pragma unroll
        for (int kn = 0; kn < 2; ++kn)
#pragma unroll
            for (int r = 0; r < 4; ++r) {
                const float e = __expf(S[kn][r] - mrow);
                s += e;
                pfv[kn * 4 + r] = (_Float16)e;
            }
        s += __shfl_xor(s, 16);
        s += __shfl_xor(s, 32);
        lrow += s;

        __builtin_amdgcn_s_setprio(1);
#pragma unroll
        for (int dvt = 0; dvt < 16; ++dvt) {
            const f16x8 vf = *(const f16x8*)&Vc[dvt * 512 + vbase];
            O[dvt] = MFMA_F16(vf, pfv, O[dvt], 0, 0, 0);
        }
        __builtin_amdgcn_s_setprio(0);
    }
#undef STAGE

    __syncthreads();   // all waves done with last tile before smem reuse
    {
        const float rl = 1.0f / lrow;
#pragma unroll
        for (int dvt = 0; dvt < 16; ++dvt) {
            ushort4 h4;
            h4.x = f2h(O[dvt][0] * rl);
            h4.y = f2h(O[dvt][1] * rl);
            h4.z = f2h(O[dvt][2] * rl);
            h4.w = f2h(O[dvt][3] * rl);
            *(ushort4*)&Os[(w * 16 + l16) * 264 + dvt * 16 + quad * 4] = h4;
        }
        if (quad == 0) {
            const int grow = b * 2048 + q0 + w * 16 + l16;
            lmp[z * 16384 + grow]        = lrow;
            lmp[(nz + z) * 16384 + grow] = mrow;
        }
    }
    __syncthreads();

    u16* __restrict__ Oz = Op + (size_t)z * 4194304;
    {
        const int row = t >> 2;
#pragma unroll
        for (int i = 0; i < 8; ++i) {
            const int chunk = (t & 3) * 8 + i;
            *(int4*)&Oz[(size_t)(b * 2048 + q0 + row) * 256 + chunk * 8] =
                *(const int4*)&Os[row * 264 + chunk * 8];
        }
    }
}

// ---------------------------------------------------------------------------
// Kernel 3: combine 2 partials + out projection + LayerNorm + LeakyReLU.
// (R18/R19 structure, measured good — unchanged.)
// ---------------------------------------------------------------------------
__global__ __launch_bounds__(256, 2) void outproj_ln(
    const u16* __restrict__ Op, const float* __restrict__ lmp,
    const u16* __restrict__ Woh, const float* __restrict__ bo,
    const float* __restrict__ gamma, const float* __restrict__ beta,
    float* __restrict__ out)
{
    const int m0   = blockIdx.x * 32;
    const int t    = threadIdx.x;
    const int w    = t >> 6;
    const int rw   = w & 1;        // row-group (16 rows)
    const int cw   = w >> 1;       // col-half (128 cols)
    const int lane = t & 63;
    const int quad = lane >> 4;
    const int l16  = lane & 15;

    __shared__ __align__(16) u16 Ls[32 * 40];
    __shared__ __align__(16) u16 Ws[256 * 40];
    __shared__ _Float16 wls[2][32];
    __shared__ float part[2][16][2][2];   // [rw][row16][cw][{sh,sh2}]

    if (t < 32) {
        const float l0 = lmp[m0 + t],          l1 = lmp[16384 + m0 + t];
        const float mm0 = lmp[32768 + m0 + t], mm1 = lmp[49152 + m0 + t];
        const float mm = fmaxf(mm0, mm1);
        const float u0 = l0 * __expf(mm0 - mm);
        const float u1 = l1 * __expf(mm1 - mm);
        const float inv = 1.0f / (u0 + u1);
        wls[0][t] = (_Float16)(u0 * inv);
        wls[1][t] = (_Float16)(u1 * inv);
    }
    __syncthreads();

    f32x4 acc[8];
#pragma unroll
    for (int i = 0; i < 8; ++i) acc[i] = f32x4{0.f, 0.f, 0.f, 0.f};

    for (int kc = 0; kc < 8; ++kc) {
        if (t < 128) {
            const int row = t >> 2, cg = t & 3;
            const size_t off = (size_t)(m0 + row) * 256 + kc * 32 + cg * 8;
            const f16x8 o0 = __builtin_bit_cast(f16x8, *(const int4*)&Op[off]);
            const f16x8 o1 = __builtin_bit_cast(f16x8, *(const int4*)&Op[4194304 + off]);
            const _Float16 w0 = wls[0][row], w1 = wls[1][row];
            f16x8 lw;
#pragma unroll
            for (int j = 0; j < 8; ++j) lw[j] = o0[j] * w0 + o1[j] * w1;
            *(int4*)&Ls[row * 40 + cg * 8] = __builtin_bit_cast(int4, lw);
        }
#pragma unroll
        for (int i = 0; i < 4; ++i) {
            const int ch = i * 256 + t;
            const int row = ch >> 2, cg = ch & 3;
            *(int4*)&Ws[row * 40 + cg * 8] =
                *(const int4*)&Woh[(size_t)row * 256 + kc * 32 + cg * 8];
        }
        __syncthreads();

        const f16x8 af = *(const f16x8*)&Ls[(rw * 16 + l16) * 40 + quad * 8];
#pragma unroll
        for (int nt = 0; nt < 8; ++nt) {
            const f16x8 bf = *(const f16x8*)&Ws[((cw * 8 + nt) * 16 + l16) * 40 + quad * 8];
            acc[nt] = MFMA_F16(af, bf, acc[nt], 0, 0, 0);
        }
        __syncthreads();
    }

    float g[8], bt[8], bb[8];
#pragma unroll
    for (int nt = 0; nt < 8; ++nt) {
        const int col = cw * 128 + nt * 16 + l16;
        bb[nt] = bo[col]; g[nt] = gamma[col]; bt[nt] = beta[col];
    }

    float shv[4], sh2v[4];
#pragma unroll
    for (int r = 0; r < 4; ++r) {
        float sh = 0.f, sh2 = 0.f;
#pragma unroll
        for (int nt = 0; nt < 8; ++nt) {
            const float h = acc[nt][r] + bb[nt];
            sh  += h;
            sh2 += h * h;
        }
        sh  += __shfl_xor(sh, 1);  sh  += __shfl_xor(sh, 2);
        sh  += __shfl_xor(sh, 4);  sh  += __shfl_xor(sh, 8);
        sh2 += __shfl_xor(sh2, 1); sh2 += __shfl_xor(sh2, 2);
        sh2 += __shfl_xor(sh2, 4); sh2 += __shfl_xor(sh2, 8);
        shv[r] = sh; sh2v[r] = sh2;
    }
    if (l16 == 0) {
#pragma unroll
        for (int r = 0; r < 4; ++r) {
            part[rw][quad * 4 + r][cw][0] = shv[r];
            part[rw][quad * 4 + r][cw][1] = sh2v[r];
        }
    }
    __syncthreads();

#pragma unroll
    for (int r = 0; r < 4; ++r) {
        const float sh  = shv[r]  + part[rw][quad * 4 + r][cw ^ 1][0];
        const float sh2 = sh2v[r] + part[rw][quad * 4 + r][cw ^ 1][1];
        const float mu  = sh * (1.f / 256.f);
        const float var = fmaxf(sh2 * (1.f / 256.f) - mu * mu, 0.f);
        const float rs  = rsqrtf(var + 1e-5f);
        const size_t row = (size_t)(m0 + rw * 16 + quad * 4 + r) * 256;
#pragma unroll
        for (int nt = 0; nt < 8; ++nt) {
            const float hn = (acc[nt][r] + bb[nt] - mu) * rs * g[nt] + bt[nt];
            out[row + cw * 128 + nt * 16 + l16] = (hn >= 0.f) ? hn : 0.01f * hn;
        }
    }
}

// ---------------------------------------------------------------------------
extern "C" void kernel_launch(void* const* d_in, const int* in_sizes, int n_in,
                              void* d_out, int out_size, void* d_ws, size_t ws_size,
                              hipStream_t stream)
{
    const float* x  = (const float*)d_in[0];
    const float* Wq = (const float*)d_in[1];
    const float* bq = (const float*)d_in[2];
    const float* Wk = (const float*)d_in[3];
    const float* bk = (const float*)d_in[4];
    const float* Wv = (const float*)d_in[5];
    const float* bv = (const float*)d_in[6];
    const float* Wo = (const float*)d_in[7];
    const float* bo = (const float*)d_in[8];
    const float* gm = (const float*)d_in[9];
    const float* bt = (const float*)d_in[10];
    float* out = (float*)d_out;

    // ws layout (u16): [W4 262144][Qh 4.19M][Kh 4.19M][Vt 4.19M][Op 2x4.19M][lmp]
    // (identical footprint to the 199µs baseline)
    // Xh (8MB fp16 X) lives in d_out scratch: written by prep_w, read by
    // proj_qkv, overwritten only by outproj_ln at the very end.
    u16* W4 = (u16*)d_ws;
    u16* Qh = W4 + 262144;
    u16* Kh = Qh + 4194304;
    u16* Vt = Kh + 4194304;
    u16* Op = Vt + 4194304;
    float* lmp = (float*)(Op + 2 * 4194304);  // l[2][16384], m[2][16384]
    u16* Woh = W4 + 196608;
    u16* Xh  = (u16*)d_out;

    prep_w     <<<256,            256, 0, stream>>>(Wq, Wk, Wv, Wo, x, W4, Xh);
    proj_qkv   <<<dim3(256, 3),   256, 0, stream>>>(Xh, W4, bq, bk, bv, Qh, Kh, Vt);
    attn       <<<dim3(32, 8, 2), 256, 0, stream>>>(Qh, Kh, Vt, Op, lmp);
    outproj_ln <<<512,            256, 0, stream>>>(Op, lmp, Woh, bo, gm, bt, out);
}